// Round 1
// baseline (316.128 us; speedup 1.0000x reference)
//
#include <hip/hip_runtime.h>

typedef short s16x8 __attribute__((ext_vector_type(8)));
typedef float f32x4 __attribute__((ext_vector_type(4)));
typedef float f32x16 __attribute__((ext_vector_type(16)));

#define B_ 4
#define C_ 256
#define D_ 32
#define S_ 4096

// ---- helpers ----------------------------------------------------------------

__device__ __forceinline__ unsigned short f2b(float f) {
  // RNE float -> bf16
  union { float f; unsigned u; } v; v.f = f;
  unsigned r = v.u + 0x7fffu + ((v.u >> 16) & 1u);
  return (unsigned short)(r >> 16);
}

// 16B LDS load/store at 8B alignment (rows strided by 68/132/34 elements are
// only 8B-aligned; avoid implying 16B alignment to the compiler).
__device__ __forceinline__ s16x8 lds_ld8(const unsigned short* p) {
  union { s16x8 v; uint2 u[2]; } r;
  r.u[0] = *(const uint2*)p;
  r.u[1] = *(const uint2*)(p + 4);
  return r.v;
}
__device__ __forceinline__ void lds_st8(unsigned short* p, s16x8 v) {
  union { s16x8 v; uint2 u[2]; } r; r.v = v;
  *(uint2*)p       = r.u[0];
  *(uint2*)(p + 4) = r.u[1];
}

// ---- kernel 1: Q/K projections (fp32 VALU, small) ---------------------------
// q[b,n,o] = sum_c wq[o,c] x[b,c,n] + bq[o]  -> Qb[b][n][o] bf16
// k stored identically: Kb[b][n][o] (S = sum_o Q[i,o] K[j,o])
__global__ __launch_bounds__(256, 1)
void qk_proj_kernel(const float* __restrict__ x,
                    const float* __restrict__ wq, const float* __restrict__ bq,
                    const float* __restrict__ wk, const float* __restrict__ bk,
                    unsigned short* __restrict__ Qb, unsigned short* __restrict__ Kb) {
  __shared__ float xl[256][64];   // [c][n] fp32, stride 64 words -> 2-way banks (free)
  const int b  = blockIdx.y;
  const int n0 = blockIdx.x * 64;
  const int t  = threadIdx.x;
  const float* xb = x + ((size_t)b * C_) * S_ + n0;
  {
    const int n4 = (t & 15) * 4;
    const int cb = t >> 4;
    for (int p = 0; p < 16; ++p) {
      const int c = p * 16 + cb;
      *(f32x4*)&xl[c][n4] = *(const f32x4*)(xb + (size_t)c * S_ + n4);
    }
  }
  __syncthreads();
  const int w = t >> 6;          // wave id (uniform) -> weight rows are wave-uniform (s_loads)
  const int n = t & 63;
  const float* W            = (w < 2) ? wq : wk;
  const float* bias         = (w < 2) ? bq : bk;
  unsigned short* Ob        = (w < 2) ? Qb : Kb;
  const int o0 = (w & 1) * 16;
  float acc[16];
  #pragma unroll
  for (int i = 0; i < 16; ++i) acc[i] = 0.f;
  for (int c = 0; c < 256; ++c) {
    const float xv = xl[c][n];
    #pragma unroll
    for (int i = 0; i < 16; ++i) acc[i] += W[(o0 + i) * 256 + c] * xv;
  }
  __align__(16) unsigned short tmp[16];
  #pragma unroll
  for (int i = 0; i < 16; ++i) tmp[i] = f2b(acc[i] + bias[o0 + i]);
  unsigned short* dst = Ob + ((size_t)b * S_ + n0 + n) * 32 + o0;
  *(s16x8*)dst       = *(s16x8*)tmp;
  *(s16x8*)(dst + 8) = *(s16x8*)(tmp + 8);
}

// ---- kernel 2: V projection (bf16 MFMA GEMM) --------------------------------
// v[b,c,n] = sum_cc wv[c,cc] o[b,cc,n] + bv[c]  -> Vb[b][c][n] bf16
__global__ __launch_bounds__(256, 1)
void v_proj_kernel(const float* __restrict__ o, const float* __restrict__ wv,
                   const float* __restrict__ bv, unsigned short* __restrict__ Vb) {
  __shared__ unsigned short Wl[64][132];   // [co][k] bf16, k-half of 128 (+4 pad)
  __shared__ unsigned short Ol[64][132];   // [n][k]  bf16 (transposed stage)
  const int bx  = blockIdx.x;
  const int b   = bx >> 6;
  const int n0  = (bx & 63) * 64;
  const int co0 = blockIdx.y * 64;
  const int t   = threadIdx.x;
  const int L = t & 63, w = t >> 6;
  const int mt = w >> 1, nt = w & 1;
  const int g = L >> 5, m = L & 31;
  f32x16 acc = (f32x16)0.0f;
  for (int kh = 0; kh < 2; ++kh) {
    const int k0 = kh * 128;
    __syncthreads();
    // stage Wv tile 64x128 (row-major, coalesced)
    #pragma unroll
    for (int p = 0; p < 8; ++p) {
      const int e = p * 256 + t;
      const int co = e >> 5, c4 = (e & 31) * 4;
      f32x4 v = *(const f32x4*)(wv + (size_t)(co0 + co) * 256 + k0 + c4);
      union { unsigned short us[4]; uint2 u2; } pk;
      #pragma unroll
      for (int k = 0; k < 4; ++k) pk.us[k] = f2b(v[k]);
      *(uint2*)&Wl[co][c4] = pk.u2;
    }
    // stage O tile transposed: O[b][k0+k][n0+n] -> Ol[n][k]
    for (int p = 0; p < 32; ++p) {
      const int krow = p * 4 + (t >> 6);
      const int n    = t & 63;
      Ol[n][krow] = f2b(o[((size_t)b * C_ + k0 + krow) * S_ + n0 + n]);
    }
    __syncthreads();
    #pragma unroll
    for (int ks = 0; ks < 8; ++ks) {
      s16x8 af = lds_ld8(&Wl[mt * 32 + m][ks * 16 + g * 8]);
      s16x8 bf = lds_ld8(&Ol[nt * 32 + m][ks * 16 + g * 8]);
      acc = __builtin_amdgcn_mfma_f32_32x32x16_bf16(af, bf, acc, 0, 0, 0);
    }
  }
  #pragma unroll
  for (int reg = 0; reg < 16; ++reg) {
    const int rr = (reg & 3) + 8 * (reg >> 2) + 4 * g;  // C/D row decode (32x32)
    const int co = co0 + mt * 32 + rr;
    const float val = acc[reg] + bv[co];
    Vb[((size_t)b * C_ + co) * S_ + n0 + nt * 32 + m] = f2b(val);
  }
}

// ---- kernel 3: flash attention + residual epilogue --------------------------
// Block = 64 Q rows of one batch, 4 waves. Per j-tile (64):
//  Phase A: wave w owns rows 16w..16w+15: S = Q K^T (16x16x32), online softmax,
//           P -> LDS (bf16), alpha -> LDS.
//  Phase B: wave w owns channels 64w..64w+63: O += P V^T (32x32x16), with
//           per-row alpha rescale.
// Epilogue: O/l, *gamma, +input; LDS transpose for coalesced float4 stores.
__global__ __launch_bounds__(256, 1)
void flash_kernel(const unsigned short* __restrict__ Qb,
                  const unsigned short* __restrict__ Kb,
                  const unsigned short* __restrict__ Vb,
                  const float* __restrict__ inp,
                  const float* __restrict__ gamma,
                  float* __restrict__ out) {
  __shared__ __align__(16) unsigned char smem[49152];
  unsigned short* Kl = (unsigned short*)smem;                    // [64][40]  5120 B
  unsigned short* Vl = (unsigned short*)(smem + 5120);           // [256][68] 34816 B
  unsigned short* Pl = (unsigned short*)(smem + 5120 + 34816);   // [64][68]  8704 B
  float* alphaS = (float*)(smem + 5120 + 34816 + 8704);          // [64]
  float* lS     = alphaS + 64;                                   // [64]
  const int b  = blockIdx.y;
  const int i0 = blockIdx.x * 64;
  const int t  = threadIdx.x;
  const int L = t & 63, w = t >> 6;
  const int q4 = L >> 4, c16 = L & 15;   // 16x16 frag decode
  const int g  = L >> 5, l32 = L & 31;   // 32x32 frag decode
  const unsigned short* Kbase = Kb + (size_t)b * S_ * 32;
  const unsigned short* Vbase = Vb + (size_t)b * C_ * S_;
  // Q A-fragment (rows i0+16w+c16, k = 8*q4..+7), loaded once
  const s16x8 qf = *(const s16x8*)(Qb + ((size_t)b * S_ + i0 + w * 16 + c16) * 32 + q4 * 8);

  f32x16 acc00 = (f32x16)0.0f, acc01 = (f32x16)0.0f;  // rows 0..31  x cols {0..31,32..63} of wave's 64-ch slice
  f32x16 acc10 = (f32x16)0.0f, acc11 = (f32x16)0.0f;  // rows 32..63
  float m_run[4] = {-1e30f, -1e30f, -1e30f, -1e30f};
  float l_run[4] = {0.f, 0.f, 0.f, 0.f};

  for (int j0 = 0; j0 < S_; j0 += 64) {
    __syncthreads();
    { // stage K tile 64x32
      const int row = t >> 2, cc = (t & 3) * 8;
      s16x8 kv = *(const s16x8*)(Kbase + (size_t)(j0 + row) * 32 + cc);
      *(s16x8*)(Kl + row * 40 + cc) = kv;   // 80B rows: 16B aligned
    }
    #pragma unroll
    for (int p = 0; p < 8; ++p) { // stage V tile 256x64
      const int id = p * 256 + t;
      const int row = id >> 3, cc = (id & 7) * 8;
      s16x8 vv = *(const s16x8*)(Vbase + (size_t)row * S_ + j0 + cc);
      lds_st8(Vl + row * 68 + cc, vv);
    }
    __syncthreads();
    // ---- Phase A: scores for own 16 rows
    f32x4 sj[4];
    #pragma unroll
    for (int jt = 0; jt < 4; ++jt) {
      s16x8 kf = *(const s16x8*)(Kl + (jt * 16 + c16) * 40 + q4 * 8);
      sj[jt] = __builtin_amdgcn_mfma_f32_16x16x32_bf16(qf, kf, (f32x4)0.0f, 0, 0, 0);
    }
    float pr[4][4];
    float al[4];
    #pragma unroll
    for (int r = 0; r < 4; ++r) {
      float tm = fmaxf(fmaxf(sj[0][r], sj[1][r]), fmaxf(sj[2][r], sj[3][r]));
      #pragma unroll
      for (int d = 1; d < 16; d <<= 1) tm = fmaxf(tm, __shfl_xor(tm, d, 64));
      const float mn = fmaxf(m_run[r], tm);
      al[r] = __expf(m_run[r] - mn);
      float rs = 0.f;
      #pragma unroll
      for (int jt = 0; jt < 4; ++jt) {
        const float p = __expf(sj[jt][r] - mn);
        pr[jt][r] = p; rs += p;
      }
      #pragma unroll
      for (int d = 1; d < 16; d <<= 1) rs += __shfl_xor(rs, d, 64);
      l_run[r] = l_run[r] * al[r] + rs;
      m_run[r] = mn;
    }
    #pragma unroll
    for (int jt = 0; jt < 4; ++jt)
      #pragma unroll
      for (int r = 0; r < 4; ++r)
        Pl[(w * 16 + q4 * 4 + r) * 68 + jt * 16 + c16] = f2b(pr[jt][r]);
    if (c16 == 0) {
      #pragma unroll
      for (int r = 0; r < 4; ++r) alphaS[w * 16 + q4 * 4 + r] = al[r];
    }
    __syncthreads();
    // ---- Phase B: rescale + PV for own 64 channels
    #pragma unroll
    for (int rq = 0; rq < 4; ++rq) {
      const f32x4 a0 = *(const f32x4*)&alphaS[rq * 8 + g * 4];
      const f32x4 a1 = *(const f32x4*)&alphaS[32 + rq * 8 + g * 4];
      #pragma unroll
      for (int k = 0; k < 4; ++k) {
        acc00[rq * 4 + k] *= a0[k];
        acc01[rq * 4 + k] *= a0[k];
        acc10[rq * 4 + k] *= a1[k];
        acc11[rq * 4 + k] *= a1[k];
      }
    }
    #pragma unroll
    for (int kb = 0; kb < 4; ++kb) {
      const int ko = kb * 16 + g * 8;
      const s16x8 pf0 = lds_ld8(Pl + l32 * 68 + ko);
      const s16x8 pf1 = lds_ld8(Pl + (32 + l32) * 68 + ko);
      const s16x8 vf0 = lds_ld8(Vl + (w * 64 + l32) * 68 + ko);
      const s16x8 vf1 = lds_ld8(Vl + (w * 64 + 32 + l32) * 68 + ko);
      acc00 = __builtin_amdgcn_mfma_f32_32x32x16_bf16(pf0, vf0, acc00, 0, 0, 0);
      acc01 = __builtin_amdgcn_mfma_f32_32x32x16_bf16(pf0, vf1, acc01, 0, 0, 0);
      acc10 = __builtin_amdgcn_mfma_f32_32x32x16_bf16(pf1, vf0, acc10, 0, 0, 0);
      acc11 = __builtin_amdgcn_mfma_f32_32x32x16_bf16(pf1, vf1, acc11, 0, 0, 0);
    }
  }
  // ---- epilogue
  __syncthreads();
  if (c16 == 0) {
    #pragma unroll
    for (int r = 0; r < 4; ++r) lS[w * 16 + q4 * 4 + r] = l_run[r];
  }
  __syncthreads();
  float* scr = (float*)smem + w * (64 * 34);   // per-wave [64 c][34 i] fp32 scratch (reuses K/V/P region)
  const float gam = gamma[0];
  #pragma unroll
  for (int mtl = 0; mtl < 2; ++mtl) {
    const f32x16 a0 = mtl ? acc10 : acc00;
    const f32x16 a1 = mtl ? acc11 : acc01;
    #pragma unroll
    for (int reg = 0; reg < 16; ++reg) {
      const int rr = (reg & 3) + 8 * (reg >> 2) + 4 * g;
      scr[l32 * 34 + rr]        = a0[reg];
      scr[(32 + l32) * 34 + rr] = a1[reg];
    }
    const int cl = L >> 3;
    const int i4 = (L & 7) * 4;
    const f32x4 lv = *(const f32x4*)&lS[mtl * 32 + i4];
    f32x4 sc;
    #pragma unroll
    for (int k = 0; k < 4; ++k) sc[k] = gam / lv[k];
    #pragma unroll
    for (int p = 0; p < 8; ++p) {
      const int c = p * 8 + cl;
      union { f32x4 v; uint2 u[2]; } rv;
      rv.u[0] = *(const uint2*)&scr[c * 34 + i4];
      rv.u[1] = *(const uint2*)&scr[c * 34 + i4 + 2];
      const size_t gi = ((size_t)b * C_ + w * 64 + c) * S_ + i0 + mtl * 32 + i4;
      const f32x4 iv = *(const f32x4*)&inp[gi];
      f32x4 o4;
      #pragma unroll
      for (int k = 0; k < 4; ++k) o4[k] = rv.v[k] * sc[k] + iv[k];
      *(f32x4*)&out[gi] = o4;
    }
  }
}

// ---- launch -----------------------------------------------------------------
extern "C" void kernel_launch(void* const* d_in, const int* in_sizes, int n_in,
                              void* d_out, int out_size, void* d_ws, size_t ws_size,
                              hipStream_t stream) {
  const float* inp   = (const float*)d_in[0];
  const float* orig  = (const float*)d_in[1];
  const float* wq    = (const float*)d_in[2];
  const float* bq    = (const float*)d_in[3];
  const float* wk    = (const float*)d_in[4];
  const float* bk    = (const float*)d_in[5];
  const float* wv    = (const float*)d_in[6];
  const float* bv    = (const float*)d_in[7];
  const float* gamma = (const float*)d_in[8];
  float* out = (float*)d_out;

  unsigned short* Qb = (unsigned short*)d_ws;            // [B][S][32] bf16, 1 MB
  unsigned short* Kb = Qb + (size_t)B_ * S_ * 32;        // [B][S][32] bf16, 1 MB
  unsigned short* Vb = Kb + (size_t)B_ * S_ * 32;        // [B][C][S]  bf16, 8 MB

  qk_proj_kernel<<<dim3(64, 4), 256, 0, stream>>>(inp, wq, bq, wk, bk, Qb, Kb);
  v_proj_kernel<<<dim3(256, 4), 256, 0, stream>>>(orig, wv, bv, Vb);
  flash_kernel<<<dim3(64, 4), 256, 0, stream>>>(Qb, Kb, Vb, inp, gamma, out);
}

// Round 2
// 225.616 us; speedup vs baseline: 1.4012x; 1.4012x over previous
//
#include <hip/hip_runtime.h>

typedef short s16x8 __attribute__((ext_vector_type(8)));
typedef float f32x4 __attribute__((ext_vector_type(4)));
typedef float f32x16 __attribute__((ext_vector_type(16)));

#define B_ 4
#define C_ 256
#define S_ 4096
#define LOG2E 1.44269504088896f
#define M2 32.0f   // fixed base-2 softmax offset: p = 2^(s' - M2)

#if __has_builtin(__builtin_amdgcn_exp2f)
#define EXP2(x) __builtin_amdgcn_exp2f(x)
#else
#define EXP2(x) __exp2f(x)
#endif

// RNE float -> bf16 (used for stored tensors)
__device__ __forceinline__ unsigned short f2b(float f) {
  union { float f; unsigned u; } v; v.f = f;
  unsigned r = v.u + 0x7fffu + ((v.u >> 16) & 1u);
  return (unsigned short)(r >> 16);
}
// cheap round-half-up float -> bf16 (hot loop; ties are measure-zero here)
__device__ __forceinline__ unsigned short f2b_fast(float f) {
  union { float f; unsigned u; } v; v.f = f;
  return (unsigned short)((v.u + 0x8000u) >> 16);
}
// 16B LDS load at 8B alignment
__device__ __forceinline__ s16x8 lds_ld8(const unsigned short* p) {
  union { s16x8 v; uint2 u[2]; } r;
  r.u[0] = *(const uint2*)p;
  r.u[1] = *(const uint2*)(p + 4);
  return r.v;
}

// ---- fused QKV projection (MFMA) --------------------------------------------
// ct==0:  rows 0-31 = Q (from input, scaled by LOG2E), rows 32-63 = K (input)
// ct 1-4: rows = Wv[(ct-1)*64 .. +64) (from original)
// Qb,Kb: [B][S][32] bf16 (n-major).  Vb: [B][C][S] bf16.
__global__ __launch_bounds__(256)
void proj_kernel(const float* __restrict__ x, const float* __restrict__ orig,
                 const float* __restrict__ wq, const float* __restrict__ bq,
                 const float* __restrict__ wk, const float* __restrict__ bk,
                 const float* __restrict__ wv, const float* __restrict__ bv,
                 unsigned short* __restrict__ Qb, unsigned short* __restrict__ Kb,
                 unsigned short* __restrict__ Vb) {
  __shared__ unsigned short Al[64 * 72];
  __shared__ unsigned short Sl[64 * 72];
  const int ct = blockIdx.x >> 6;
  const int n0 = (blockIdx.x & 63) * 64;
  const int b  = blockIdx.y;
  const int t  = threadIdx.x;
  const int L = t & 63, w = t >> 6;
  const int mt = w >> 1, nt = w & 1;      // wave quadrant of 64x64 out tile
  const int g = L >> 5, l32 = L & 31;
  const float* srcb = ((ct == 0) ? x : orig) + (size_t)b * C_ * S_;
  f32x16 acc = (f32x16)0.0f;

  for (int kc = 0; kc < 4; ++kc) {
    const int k0 = kc * 64;
    __syncthreads();
    // stage weights: Al[row][c] (64x64)
    #pragma unroll
    for (int rep = 0; rep < 4; ++rep) {
      const int idx = rep * 256 + t;
      const int row = idx >> 4, c4 = (idx & 15) * 4;
      const float* wsrc; int wrow;
      if (ct == 0) {
        if (row < 32) { wsrc = wq; wrow = row; } else { wsrc = wk; wrow = row - 32; }
      } else { wsrc = wv; wrow = (ct - 1) * 64 + row; }
      f32x4 v = *(const f32x4*)(wsrc + (size_t)wrow * 256 + k0 + c4);
      union { unsigned short us[4]; uint2 u2; } pk;
      #pragma unroll
      for (int i = 0; i < 4; ++i) pk.us[i] = f2b(v[i]);
      *(uint2*)&Al[row * 72 + c4] = pk.u2;
    }
    // stage source transposed: Sl[n][c] <- srcb[k0+c][n0+n]
    #pragma unroll
    for (int rep = 0; rep < 4; ++rep) {
      const int c  = rep * 16 + (t >> 4);
      const int n4 = (t & 15) * 4;
      f32x4 v = *(const f32x4*)(srcb + (size_t)(k0 + c) * S_ + n0 + n4);
      #pragma unroll
      for (int i = 0; i < 4; ++i) Sl[(n4 + i) * 72 + c] = f2b(v[i]);
    }
    __syncthreads();
    #pragma unroll
    for (int ks = 0; ks < 4; ++ks) {
      s16x8 af = lds_ld8(&Al[(mt * 32 + l32) * 72 + ks * 16 + g * 8]);
      s16x8 bf = lds_ld8(&Sl[(nt * 32 + l32) * 72 + ks * 16 + g * 8]);
      acc = __builtin_amdgcn_mfma_f32_32x32x16_bf16(af, bf, acc, 0, 0, 0);
    }
  }
  const int n = n0 + nt * 32 + l32;
  #pragma unroll
  for (int reg = 0; reg < 16; ++reg) {
    const int rr = (reg & 3) + 8 * (reg >> 2) + 4 * g;   // row within 32-tile
    if (ct == 0) {
      if (mt == 0) {
        const float val = (acc[reg] + bq[rr]) * LOG2E;
        Qb[((size_t)b * S_ + n) * 32 + rr] = f2b(val);
      } else {
        const float val = acc[reg] + bk[rr];
        Kb[((size_t)b * S_ + n) * 32 + rr] = f2b(val);
      }
    } else {
      const int co = (ct - 1) * 64 + mt * 32 + rr;
      const float val = acc[reg] + bv[co];
      Vb[((size_t)b * C_ + co) * S_ + n] = f2b(val);
    }
  }
}

// ---- flash attention, fixed-offset base-2 softmax ---------------------------
// 512 threads (8 waves), i-tile 64, grid 256 (1 block/CU), j-tile 64.
// Phase A: wave (rh,jh) computes scores for rows rh*16.. x j-half jh*32..;
//          p = exp2(s - M2); no max tracking, no rescale; l kept per-lane.
// Phase B: wave w owns channels w*32..; V fragments straight from global.
struct FlashSmem {
  union {
    unsigned short P[64 * 72];   // bf16 probabilities (j-tile)
    float scr[64 * 258];         // epilogue transpose [i][ch]
  } u;
  float lpart[2][64];
};

__global__ __launch_bounds__(512, 2)
void flash_kernel(const unsigned short* __restrict__ Qb,
                  const unsigned short* __restrict__ Kb,
                  const unsigned short* __restrict__ Vb,
                  const float* __restrict__ inp,
                  const float* __restrict__ gamma,
                  float* __restrict__ out) {
  __shared__ FlashSmem sm;
  // XCD swizzle: each XCD pair handles one batch (V[b]=2MB fits 4MB L2)
  const int l  = blockIdx.x;
  const int b  = (l & 7) >> 1;
  const int i0 = ((l >> 3) * 2 + (l & 1)) * 64;
  const int t  = threadIdx.x;
  const int L = t & 63, w = t >> 6;
  const int q4 = L >> 4, c16 = L & 15;
  const int g  = L >> 5, l32 = L & 31;
  const int rh = w & 3, jh = w >> 2;            // phase A role
  const unsigned short* Kbase = Kb + (size_t)b * S_ * 32;
  const unsigned short* Vrow  = Vb + ((size_t)b * C_ + w * 32 + l32) * S_;
  const s16x8 qf = *(const s16x8*)(Qb + ((size_t)b * S_ + i0 + rh * 16 + c16) * 32 + q4 * 8);

  f32x16 acc0 = (f32x16)0.0f, acc1 = (f32x16)0.0f;
  float lp[4] = {0.f, 0.f, 0.f, 0.f};

  for (int j0 = 0; j0 < S_; j0 += 64) {
    // prefetch K and V fragments (global; no LDS dependency)
    const s16x8 kf0 = *(const s16x8*)(Kbase + (size_t)(j0 + jh * 32 + c16) * 32 + q4 * 8);
    const s16x8 kf1 = *(const s16x8*)(Kbase + (size_t)(j0 + jh * 32 + 16 + c16) * 32 + q4 * 8);
    s16x8 vf[4];
    #pragma unroll
    for (int kb = 0; kb < 4; ++kb)
      vf[kb] = *(const s16x8*)(Vrow + j0 + kb * 16 + g * 8);
    __syncthreads();   // previous Phase B done reading P
    // Phase A: scores with C-init = -M2  ->  s' - M2 directly
    f32x4 cinit = (f32x4)(-M2);
    f32x4 s0 = __builtin_amdgcn_mfma_f32_16x16x32_bf16(qf, kf0, cinit, 0, 0, 0);
    f32x4 s1 = __builtin_amdgcn_mfma_f32_16x16x32_bf16(qf, kf1, cinit, 0, 0, 0);
    #pragma unroll
    for (int r = 0; r < 4; ++r) {
      const float p0 = EXP2(s0[r]);
      const float p1 = EXP2(s1[r]);
      lp[r] += p0 + p1;
      const int row = rh * 16 + q4 * 4 + r;
      sm.u.P[row * 72 + jh * 32 + c16]      = f2b_fast(p0);
      sm.u.P[row * 72 + jh * 32 + 16 + c16] = f2b_fast(p1);
    }
    __syncthreads();   // P ready
    // Phase B: O += P * V^T for own 32 channels
    #pragma unroll
    for (int kb = 0; kb < 4; ++kb) {
      const int ko = kb * 16 + g * 8;
      const s16x8 pf0 = lds_ld8(sm.u.P + l32 * 72 + ko);
      const s16x8 pf1 = lds_ld8(sm.u.P + (32 + l32) * 72 + ko);
      acc0 = __builtin_amdgcn_mfma_f32_32x32x16_bf16(pf0, vf[kb], acc0, 0, 0, 0);
      acc1 = __builtin_amdgcn_mfma_f32_32x32x16_bf16(pf1, vf[kb], acc1, 0, 0, 0);
    }
  }
  // ---- l reduction: sum over the 16 c16-lanes; write per-(jh,row) partial
  #pragma unroll
  for (int r = 0; r < 4; ++r) {
    float v = lp[r];
    #pragma unroll
    for (int d = 1; d < 16; d <<= 1) v += __shfl_xor(v, d, 64);
    lp[r] = v;
  }
  __syncthreads();   // last Phase B done with P before scr overwrites it
  if (c16 == 0) {
    #pragma unroll
    for (int r = 0; r < 4; ++r) sm.lpart[jh][rh * 16 + q4 * 4 + r] = lp[r];
  }
  // ---- epilogue: transpose accs through LDS, scale by gamma/l, add input
  #pragma unroll
  for (int reg = 0; reg < 16; ++reg) {
    const int rr = (reg & 3) + 8 * (reg >> 2) + 4 * g;
    sm.u.scr[rr * 258 + w * 32 + l32]        = acc0[reg];
    sm.u.scr[(32 + rr) * 258 + w * 32 + l32] = acc1[reg];
  }
  __syncthreads();
  const float gam = gamma[0];
  const float li = sm.lpart[0][L] + sm.lpart[1][L];
  const float sc = gam / li;
  #pragma unroll
  for (int p = 0; p < 32; ++p) {
    const int ch = w * 32 + p;
    const size_t gi = ((size_t)b * C_ + ch) * S_ + i0 + L;
    out[gi] = sm.u.scr[L * 258 + ch] * sc + inp[gi];
  }
}

// ---- launch -----------------------------------------------------------------
extern "C" void kernel_launch(void* const* d_in, const int* in_sizes, int n_in,
                              void* d_out, int out_size, void* d_ws, size_t ws_size,
                              hipStream_t stream) {
  const float* inp   = (const float*)d_in[0];
  const float* orig  = (const float*)d_in[1];
  const float* wq    = (const float*)d_in[2];
  const float* bq    = (const float*)d_in[3];
  const float* wk    = (const float*)d_in[4];
  const float* bk    = (const float*)d_in[5];
  const float* wv    = (const float*)d_in[6];
  const float* bv    = (const float*)d_in[7];
  const float* gamma = (const float*)d_in[8];
  float* out = (float*)d_out;

  unsigned short* Qb = (unsigned short*)d_ws;            // [B][S][32] bf16, 1 MB
  unsigned short* Kb = Qb + (size_t)B_ * S_ * 32;        // [B][S][32] bf16, 1 MB
  unsigned short* Vb = Kb + (size_t)B_ * S_ * 32;        // [B][C][S]  bf16, 8 MB

  proj_kernel<<<dim3(320, 4), 256, 0, stream>>>(inp, orig, wq, bq, wk, bk, wv, bv, Qb, Kb, Vb);
  flash_kernel<<<256, 512, 0, stream>>>(Qb, Kb, Vb, inp, gamma, out);
}

// Round 3
// 164.912 us; speedup vs baseline: 1.9170x; 1.3681x over previous
//
#include <hip/hip_runtime.h>

typedef short s16x8 __attribute__((ext_vector_type(8)));
typedef float f32x4 __attribute__((ext_vector_type(4)));
typedef float f32x16 __attribute__((ext_vector_type(16)));

#define B_ 4
#define C_ 256
#define S_ 4096
#define LOG2E 1.44269504088896f
#define M2 32.0f   // fixed base-2 softmax offset: p = 2^(s' - M2)

#if __has_builtin(__builtin_amdgcn_exp2f)
#define EXP2(x) __builtin_amdgcn_exp2f(x)
#else
#define EXP2(x) __exp2f(x)
#endif

// RNE float -> bf16
__device__ __forceinline__ unsigned short f2b(float f) {
  union { float f; unsigned u; } v; v.f = f;
  unsigned r = v.u + 0x7fffu + ((v.u >> 16) & 1u);
  return (unsigned short)(r >> 16);
}
// cheap round-half-up float -> bf16 (hot loop)
__device__ __forceinline__ unsigned short f2b_fast(float f) {
  union { float f; unsigned u; } v; v.f = f;
  return (unsigned short)((v.u + 0x8000u) >> 16);
}
// 16B LDS load at 8B alignment (rows strided by 68 shorts = 136B)
__device__ __forceinline__ s16x8 lds_ld8(const unsigned short* p) {
  union { s16x8 v; uint2 u[2]; } r;
  r.u[0] = *(const uint2*)p;
  r.u[1] = *(const uint2*)(p + 4);
  return r.v;
}

// ---- fused QKV projection (MFMA) --------------------------------------------
// ct==0:  rows 0-31 = Q (scaled by LOG2E), rows 32-63 = K (from input)
// ct 1-4: rows = Wv[(ct-1)*64 .. +64) (from original)
// Qb,Kb: [B][S][32] bf16 (n-major).
// Vf: fragment-order tiles: [b][jt][cg][vv][kb][lane64][8] bf16 (8 MB), where
//     element = V[ch = cg*64+vv*32+(lane&31)][j = jt*64 + kb*16 + (lane>>5)*8 + e]
__global__ __launch_bounds__(256)
void proj_kernel(const float* __restrict__ x, const float* __restrict__ orig,
                 const float* __restrict__ wq, const float* __restrict__ bq,
                 const float* __restrict__ wk, const float* __restrict__ bk,
                 const float* __restrict__ wv, const float* __restrict__ bv,
                 unsigned short* __restrict__ Qb, unsigned short* __restrict__ Kb,
                 unsigned short* __restrict__ Vf) {
  __shared__ unsigned short Al[64 * 68];
  __shared__ unsigned short Sl[64 * 68];
  const int ct = blockIdx.x >> 6;
  const int jt = blockIdx.x & 63;
  const int n0 = jt * 64;
  const int b  = blockIdx.y;
  const int t  = threadIdx.x;
  const int L = t & 63, w = t >> 6;
  const int mt = w >> 1, nt = w & 1;
  const int g = L >> 5, l32 = L & 31;
  const float* srcb = ((ct == 0) ? x : orig) + (size_t)b * C_ * S_;
  f32x16 acc = (f32x16)0.0f;

  for (int kc = 0; kc < 4; ++kc) {
    const int k0 = kc * 64;
    __syncthreads();
    // stage weights Al[row][c] (64x64)
    #pragma unroll
    for (int rep = 0; rep < 4; ++rep) {
      const int idx = rep * 256 + t;
      const int row = idx >> 4, c4 = (idx & 15) * 4;
      const float* wsrc; int wrow;
      if (ct == 0) {
        if (row < 32) { wsrc = wq; wrow = row; } else { wsrc = wk; wrow = row - 32; }
      } else { wsrc = wv; wrow = (ct - 1) * 64 + row; }
      f32x4 v = *(const f32x4*)(wsrc + (size_t)wrow * 256 + k0 + c4);
      union { unsigned short us[4]; uint2 u2; } pk;
      #pragma unroll
      for (int i = 0; i < 4; ++i) pk.us[i] = f2b(v[i]);
      *(uint2*)&Al[row * 68 + c4] = pk.u2;
    }
    // stage source transposed Sl[n][c], vectorized 8B LDS writes
    {
      const int c4 = (t >> 4) * 4;
      const int n4 = (t & 15) * 4;
      f32x4 v0 = *(const f32x4*)(srcb + (size_t)(k0 + c4 + 0) * S_ + n0 + n4);
      f32x4 v1 = *(const f32x4*)(srcb + (size_t)(k0 + c4 + 1) * S_ + n0 + n4);
      f32x4 v2 = *(const f32x4*)(srcb + (size_t)(k0 + c4 + 2) * S_ + n0 + n4);
      f32x4 v3 = *(const f32x4*)(srcb + (size_t)(k0 + c4 + 3) * S_ + n0 + n4);
      #pragma unroll
      for (int k = 0; k < 4; ++k) {
        union { unsigned short us[4]; uint2 u2; } pk;
        pk.us[0] = f2b(v0[k]); pk.us[1] = f2b(v1[k]);
        pk.us[2] = f2b(v2[k]); pk.us[3] = f2b(v3[k]);
        *(uint2*)&Sl[(n4 + k) * 68 + c4] = pk.u2;
      }
    }
    __syncthreads();
    #pragma unroll
    for (int ks = 0; ks < 4; ++ks) {
      s16x8 af = lds_ld8(&Al[(mt * 32 + l32) * 68 + ks * 16 + g * 8]);
      s16x8 bf = lds_ld8(&Sl[(nt * 32 + l32) * 68 + ks * 16 + g * 8]);
      acc = __builtin_amdgcn_mfma_f32_32x32x16_bf16(af, bf, acc, 0, 0, 0);
    }
  }
  __syncthreads();   // LDS free; reuse Al as repack buffer
  unsigned short* Rl = Al;
  const int n = nt * 32 + l32;
  if (ct == 0) {
    // dump [n][ch]: ch 0..31 = Q, 32..63 = K
    #pragma unroll
    for (int reg = 0; reg < 16; ++reg) {
      const int rr = (reg & 3) + 8 * (reg >> 2) + 4 * g;
      const float val = (mt == 0) ? (acc[reg] + bq[rr]) * LOG2E : acc[reg] + bk[rr];
      Rl[n * 68 + mt * 32 + rr] = f2b(val);
    }
    __syncthreads();
    const int nn = t >> 2, ch0 = (t & 3) * 16;
    s16x8 a = lds_ld8(Rl + nn * 68 + ch0);
    s16x8 c = lds_ld8(Rl + nn * 68 + ch0 + 8);
    unsigned short* dst = (ch0 < 32)
        ? Qb + ((size_t)b * S_ + n0 + nn) * 32 + ch0
        : Kb + ((size_t)b * S_ + n0 + nn) * 32 + (ch0 - 32);
    *(s16x8*)dst = a;
    *(s16x8*)(dst + 8) = c;
  } else {
    const int cg = ct - 1;
    // dump [ch][j]
    #pragma unroll
    for (int reg = 0; reg < 16; ++reg) {
      const int rr = (reg & 3) + 8 * (reg >> 2) + 4 * g;
      const int ch = mt * 32 + rr;
      Rl[ch * 68 + n] = f2b(acc[reg] + bv[cg * 64 + ch]);
    }
    __syncthreads();
    unsigned short* grp = Vf + ((size_t)(b * 64 + jt) * 4 + cg) * 4096;
    #pragma unroll
    for (int k = 0; k < 2; ++k) {
      const int G = t * 2 + k;
      const int vv = G >> 8, kb = (G >> 6) & 3, Lf = G & 63;
      const int ch64 = vv * 32 + (Lf & 31);
      const int j64  = kb * 16 + (Lf >> 5) * 8;
      s16x8 v = lds_ld8(Rl + ch64 * 68 + j64);
      *(s16x8*)(grp + G * 8) = v;
    }
  }
}

// ---- flash attention, fixed-offset base-2 softmax ---------------------------
// 512 threads (8 waves), i-tile 64, grid 256 (2 blocks/CU), j-tile 64.
// Phase A: wave (rh,jh): rows rh*16.. x j-half jh*32..; p = exp2(s-M2); P->LDS.
// Phase B: wave (dup,cg): 64 ch (cg) x 64 i, kb-split (dup) -> 4 accs;
//          V fragments via single coalesced global loads (pre-swizzled Vf).
union FlashU {
  unsigned short P[64 * 68];   // 8704 B
  float scr[2][32 * 258];      // 66048 B (epilogue, 2 dup planes x 32 i-rows)
};

__global__ __launch_bounds__(512, 4)
void flash_kernel(const unsigned short* __restrict__ Qb,
                  const unsigned short* __restrict__ Kb,
                  const unsigned short* __restrict__ Vf,
                  const float* __restrict__ inp,
                  const float* __restrict__ gamma,
                  float* __restrict__ out) {
  __shared__ FlashU sm;
  __shared__ float lpart[2][64];
  __shared__ float invl[64];
  const int l  = blockIdx.x;
  const int b  = (l & 7) >> 1;                       // XCD pair per batch
  const int i0 = ((l >> 3) * 2 + (l & 1)) * 64;
  const int t  = threadIdx.x;
  const int L = t & 63, w = t >> 6;
  const int q4 = L >> 4, c16 = L & 15;
  const int g  = L >> 5, l32 = L & 31;
  const int rh = w & 3, jh = w >> 2;                 // phase A role
  const int cg = w & 3, dup = w >> 2;                // phase B role
  const float gam = gamma[0];
  const unsigned short* Kbase = Kb + (size_t)b * S_ * 32;
  const s16x8 qf = *(const s16x8*)(Qb + ((size_t)b * S_ + i0 + rh * 16 + c16) * 32 + q4 * 8);

  f32x16 acc00 = (f32x16)0.0f, acc01 = (f32x16)0.0f;  // i 0..31  x ch {vv0,vv1}
  f32x16 acc10 = (f32x16)0.0f, acc11 = (f32x16)0.0f;  // i 32..63
  float lp[4] = {0.f, 0.f, 0.f, 0.f};

  // preload K frags for j0=0
  s16x8 kc0 = *(const s16x8*)(Kbase + (size_t)(jh * 32 + c16) * 32 + q4 * 8);
  s16x8 kc1 = *(const s16x8*)(Kbase + (size_t)(jh * 32 + 16 + c16) * 32 + q4 * 8);

  for (int j0 = 0; j0 < S_; j0 += 64) {
    const int jt = j0 >> 6;
    // prefetch next-iter K frags (consumed next phase A)
    const int jn = (j0 + 64 < S_) ? j0 + 64 : j0;
    s16x8 kn0 = *(const s16x8*)(Kbase + (size_t)(jn + jh * 32 + c16) * 32 + q4 * 8);
    s16x8 kn1 = *(const s16x8*)(Kbase + (size_t)(jn + jh * 32 + 16 + c16) * 32 + q4 * 8);
    // V fragments: one coalesced 1KB load each (pre-swizzled layout)
    const unsigned short* vbase = Vf + ((size_t)(b * 64 + jt) * 4 + cg) * 4096;
    s16x8 vf00 = *(const s16x8*)(vbase + (dup * 2 + 0) * 512 + L * 8);           // vv=0,kk=0
    s16x8 vf01 = *(const s16x8*)(vbase + 2048 + (dup * 2 + 0) * 512 + L * 8);    // vv=1,kk=0
    s16x8 vf10 = *(const s16x8*)(vbase + (dup * 2 + 1) * 512 + L * 8);           // vv=0,kk=1
    s16x8 vf11 = *(const s16x8*)(vbase + 2048 + (dup * 2 + 1) * 512 + L * 8);    // vv=1,kk=1
    // ---- Phase A
    f32x4 cinit = (f32x4)(-M2);
    f32x4 s0 = __builtin_amdgcn_mfma_f32_16x16x32_bf16(qf, kc0, cinit, 0, 0, 0);
    f32x4 s1 = __builtin_amdgcn_mfma_f32_16x16x32_bf16(qf, kc1, cinit, 0, 0, 0);
    #pragma unroll
    for (int r = 0; r < 4; ++r) {
      const float p0 = EXP2(s0[r]);
      const float p1 = EXP2(s1[r]);
      lp[r] += p0 + p1;
      const int row = rh * 16 + q4 * 4 + r;
      sm.P[row * 68 + jh * 32 + c16]      = f2b_fast(p0);
      sm.P[row * 68 + jh * 32 + 16 + c16] = f2b_fast(p1);
    }
    __syncthreads();   // P visible (also drains vf, needed immediately)
    // ---- Phase B: kb-split (dup), 2x2 register blocking
    {
      const int ko0 = (dup * 2 + 0) * 16 + g * 8;
      const s16x8 pf0 = lds_ld8(sm.P + l32 * 68 + ko0);
      const s16x8 pf1 = lds_ld8(sm.P + (32 + l32) * 68 + ko0);
      acc00 = __builtin_amdgcn_mfma_f32_32x32x16_bf16(pf0, vf00, acc00, 0, 0, 0);
      acc01 = __builtin_amdgcn_mfma_f32_32x32x16_bf16(pf0, vf01, acc01, 0, 0, 0);
      acc10 = __builtin_amdgcn_mfma_f32_32x32x16_bf16(pf1, vf00, acc10, 0, 0, 0);
      acc11 = __builtin_amdgcn_mfma_f32_32x32x16_bf16(pf1, vf01, acc11, 0, 0, 0);
    }
    {
      const int ko1 = (dup * 2 + 1) * 16 + g * 8;
      const s16x8 pf0 = lds_ld8(sm.P + l32 * 68 + ko1);
      const s16x8 pf1 = lds_ld8(sm.P + (32 + l32) * 68 + ko1);
      acc00 = __builtin_amdgcn_mfma_f32_32x32x16_bf16(pf0, vf10, acc00, 0, 0, 0);
      acc01 = __builtin_amdgcn_mfma_f32_32x32x16_bf16(pf0, vf11, acc01, 0, 0, 0);
      acc10 = __builtin_amdgcn_mfma_f32_32x32x16_bf16(pf1, vf10, acc10, 0, 0, 0);
      acc11 = __builtin_amdgcn_mfma_f32_32x32x16_bf16(pf1, vf11, acc11, 0, 0, 0);
    }
    __syncthreads();   // P consumed
    kc0 = kn0; kc1 = kn1;
  }
  // ---- l reduction
  #pragma unroll
  for (int r = 0; r < 4; ++r) {
    float v = lp[r];
    #pragma unroll
    for (int d = 1; d < 16; d <<= 1) v += __shfl_xor(v, d, 64);
    lp[r] = v;
  }
  if (c16 == 0) {
    #pragma unroll
    for (int r = 0; r < 4; ++r) lpart[jh][rh * 16 + q4 * 4 + r] = lp[r];
  }
  __syncthreads();
  if (t < 64) invl[t] = gam / (lpart[0][t] + lpart[1][t]);
  // ---- epilogue: 2 passes over i-halves; dup planes summed at store
  #pragma unroll
  for (int h = 0; h < 2; ++h) {
    const f32x16 a0 = h ? acc10 : acc00;
    const f32x16 a1 = h ? acc11 : acc01;
    float* pl = sm.scr[dup];
    #pragma unroll
    for (int reg = 0; reg < 16; ++reg) {
      const int rr = (reg & 3) + 8 * (reg >> 2) + 4 * g;
      pl[rr * 258 + cg * 64 + l32]      = a0[reg];
      pl[rr * 258 + cg * 64 + 32 + l32] = a1[reg];
    }
    __syncthreads();   // (first pass also publishes invl)
    const int ch = t >> 1;
    const int il16 = (t & 1) * 16;
    #pragma unroll
    for (int q = 0; q < 4; ++q) {
      const int iloc = il16 + q * 4;
      const size_t gi = ((size_t)b * C_ + ch) * S_ + i0 + h * 32 + iloc;
      const f32x4 iv = *(const f32x4*)(inp + gi);
      f32x4 o;
      #pragma unroll
      for (int k = 0; k < 4; ++k) {
        const int il = iloc + k;
        o[k] = (sm.scr[0][il * 258 + ch] + sm.scr[1][il * 258 + ch]) * invl[h * 32 + il] + iv[k];
      }
      *(f32x4*)(out + gi) = o;
    }
    __syncthreads();   // scr free for next pass
  }
}

// ---- launch -----------------------------------------------------------------
extern "C" void kernel_launch(void* const* d_in, const int* in_sizes, int n_in,
                              void* d_out, int out_size, void* d_ws, size_t ws_size,
                              hipStream_t stream) {
  const float* inp   = (const float*)d_in[0];
  const float* orig  = (const float*)d_in[1];
  const float* wq    = (const float*)d_in[2];
  const float* bq    = (const float*)d_in[3];
  const float* wk    = (const float*)d_in[4];
  const float* bk    = (const float*)d_in[5];
  const float* wv    = (const float*)d_in[6];
  const float* bv    = (const float*)d_in[7];
  const float* gamma = (const float*)d_in[8];
  float* out = (float*)d_out;

  unsigned short* Qb = (unsigned short*)d_ws;            // [B][S][32] bf16, 1 MB
  unsigned short* Kb = Qb + (size_t)B_ * S_ * 32;        // [B][S][32] bf16, 1 MB
  unsigned short* Vf = Kb + (size_t)B_ * S_ * 32;        // frag-tiled V, 8 MB

  proj_kernel<<<dim3(320, 4), 256, 0, stream>>>(inp, orig, wq, bq, wk, bk, wv, bv, Qb, Kb, Vf);
  flash_kernel<<<256, 512, 0, stream>>>(Qb, Kb, Vf, inp, gamma, out);
}